// Round 1
// baseline (1363.114 us; speedup 1.0000x reference)
//
#include <hip/hip_runtime.h>
#include <hip/hip_bf16.h>
#include <math.h>

// Problem constants (fixed by the reference)
constexpr int B_  = 16;
constexpr int C_  = 512;
constexpr int Hh  = 32;
constexpr int Ww  = 32;
constexpr int N_  = Hh * Ww;   // 1024 tokens
constexpr int NH_ = 8;
constexpr int HD_ = 64;        // head dim

// ---------------------------------------------------------------------------
// Kernel 1: QKV projection.  Y[b,n,co] = sum_c x[b,c,n] * W[c,co] + bias[co]
// x is [B, C, N] in memory; output Q/K/V are [B, N, C] (token-major rows).
// 64x64 tile, BK=16, 256 threads, 4x4 accum per thread. grid=(128, B, 3)
// ---------------------------------------------------------------------------
__global__ __launch_bounds__(256) void qkv_kernel(
    const float* __restrict__ x,
    const float* __restrict__ Wq, const float* __restrict__ bq,
    const float* __restrict__ Wk, const float* __restrict__ bk,
    const float* __restrict__ Wv, const float* __restrict__ bv,
    float* __restrict__ Q, float* __restrict__ K, float* __restrict__ V)
{
    const int b     = blockIdx.y;
    const int which = blockIdx.z;
    const float* W; const float* bias; float* Y;
    if (which == 0)      { W = Wq; bias = bq; Y = Q; }
    else if (which == 1) { W = Wk; bias = bk; Y = K; }
    else                 { W = Wv; bias = bv; Y = V; }

    const int tiles_n = C_ / 64;            // 8 cout tiles
    const int tm = blockIdx.x / tiles_n;    // token tile 0..15
    const int tn = blockIdx.x % tiles_n;    // cout tile 0..7
    const int m0 = tm * 64, n0 = tn * 64;

    __shared__ float As[16][65];   // As[kk][m]
    __shared__ float Bs[16][65];   // Bs[kk][co]

    const int tid = threadIdx.x;
    const int tx = tid & 15, ty = tid >> 4;

    float acc[4][4] = {};
    const float* xb = x + (size_t)b * C_ * N_;

    for (int k0 = 0; k0 < C_; k0 += 16) {
        #pragma unroll
        for (int i = 0; i < 4; ++i) {
            int idx = i * 256 + tid;          // 0..1023
            int kk = idx >> 6, m = idx & 63;  // consecutive tid -> consecutive m/co
            As[kk][m] = xb[(size_t)(k0 + kk) * N_ + m0 + m];
            Bs[kk][m] = W[(size_t)(k0 + kk) * C_ + n0 + m];
        }
        __syncthreads();
        #pragma unroll
        for (int kk = 0; kk < 16; ++kk) {
            float a[4], bb[4];
            #pragma unroll
            for (int i = 0; i < 4; ++i) a[i]  = As[kk][ty * 4 + i];
            #pragma unroll
            for (int j = 0; j < 4; ++j) bb[j] = Bs[kk][tx * 4 + j];
            #pragma unroll
            for (int i = 0; i < 4; ++i)
                #pragma unroll
                for (int j = 0; j < 4; ++j)
                    acc[i][j] = fmaf(a[i], bb[j], acc[i][j]);
        }
        __syncthreads();
    }

    float* Yb = Y + (size_t)b * N_ * C_;
    #pragma unroll
    for (int i = 0; i < 4; ++i) {
        int m = m0 + ty * 4 + i;
        float4 r;
        r.x = acc[i][0] + bias[n0 + tx * 4 + 0];
        r.y = acc[i][1] + bias[n0 + tx * 4 + 1];
        r.z = acc[i][2] + bias[n0 + tx * 4 + 2];
        r.w = acc[i][3] + bias[n0 + tx * 4 + 3];
        *(float4*)&Yb[(size_t)m * C_ + n0 + tx * 4] = r;
    }
}

// ---------------------------------------------------------------------------
// Kernel 2: flash-style attention per (q-tile 64, head, batch).
// Q/K/V are [B, N, C] with head h at columns h*64..h*64+63.
// Online softmax over 16 chunks of 64 keys. grid=(16, NH, B)
// ---------------------------------------------------------------------------
__global__ __launch_bounds__(256) void attn_kernel(
    const float* __restrict__ Q, const float* __restrict__ K,
    const float* __restrict__ V, float* __restrict__ Obuf)
{
    const int qt = blockIdx.x;   // 0..15
    const int h  = blockIdx.y;   // 0..7
    const int b  = blockIdx.z;   // 0..15
    const int q0 = qt * 64;

    __shared__ float Qs[64][65];
    __shared__ float Ks[64][65];
    __shared__ float Vs[64][65];
    __shared__ float Ps[64][65];
    __shared__ float m_run[64], l_run[64], rowscale[64];

    const int tid = threadIdx.x;
    const int tx = tid & 15, ty = tid >> 4;

    const float* Qb = Q + (size_t)b * N_ * C_ + h * HD_;
    const float* Kb = K + (size_t)b * N_ * C_ + h * HD_;
    const float* Vb = V + (size_t)b * N_ * C_ + h * HD_;

    #pragma unroll
    for (int i = 0; i < 16; ++i) {
        int idx = i * 256 + tid;            // 0..4095
        int r = idx >> 6, d = idx & 63;     // consecutive tid -> consecutive d
        Qs[r][d] = Qb[(size_t)(q0 + r) * C_ + d];
    }
    if (tid < 64) { m_run[tid] = -INFINITY; l_run[tid] = 0.f; }
    __syncthreads();

    float acc[4][4] = {};

    for (int c0 = 0; c0 < N_; c0 += 64) {
        // load K,V chunk
        #pragma unroll
        for (int i = 0; i < 16; ++i) {
            int idx = i * 256 + tid;
            int r = idx >> 6, d = idx & 63;
            Ks[r][d] = Kb[(size_t)(c0 + r) * C_ + d];
            Vs[r][d] = Vb[(size_t)(c0 + r) * C_ + d];
        }
        __syncthreads();

        // S = (Q . K^T) * rsqrt(HD)
        float s[4][4] = {};
        for (int d = 0; d < 64; ++d) {
            float qv[4], kv[4];
            #pragma unroll
            for (int i = 0; i < 4; ++i) qv[i] = Qs[ty * 4 + i][d];
            #pragma unroll
            for (int j = 0; j < 4; ++j) kv[j] = Ks[tx * 4 + j][d];
            #pragma unroll
            for (int i = 0; i < 4; ++i)
                #pragma unroll
                for (int j = 0; j < 4; ++j)
                    s[i][j] = fmaf(qv[i], kv[j], s[i][j]);
        }
        #pragma unroll
        for (int i = 0; i < 4; ++i)
            #pragma unroll
            for (int j = 0; j < 4; ++j)
                Ps[ty * 4 + i][tx * 4 + j] = s[i][j] * 0.125f;
        __syncthreads();

        // per-row online-softmax stats (4 lanes per row)
        {
            int r = tid >> 2, qq = tid & 3;
            float mx = -INFINITY;
            #pragma unroll
            for (int t = 0; t < 16; ++t) mx = fmaxf(mx, Ps[r][qq * 16 + t]);
            mx = fmaxf(mx, __shfl_xor(mx, 1));
            mx = fmaxf(mx, __shfl_xor(mx, 2));
            float m_old = m_run[r];
            float m_new = fmaxf(m_old, mx);
            float sum = 0.f;
            #pragma unroll
            for (int t = 0; t < 16; ++t) {
                float p = __expf(Ps[r][qq * 16 + t] - m_new);
                Ps[r][qq * 16 + t] = p;
                sum += p;
            }
            sum += __shfl_xor(sum, 1);
            sum += __shfl_xor(sum, 2);
            if (qq == 0) {
                float sc = __expf(m_old - m_new);
                rowscale[r] = sc;
                l_run[r] = l_run[r] * sc + sum;
                m_run[r] = m_new;
            }
        }
        __syncthreads();

        // O = O*rowscale + P . V
        #pragma unroll
        for (int i = 0; i < 4; ++i) {
            float sc = rowscale[ty * 4 + i];
            #pragma unroll
            for (int j = 0; j < 4; ++j) acc[i][j] *= sc;
        }
        for (int c = 0; c < 64; ++c) {
            float pv[4], vv[4];
            #pragma unroll
            for (int i = 0; i < 4; ++i) pv[i] = Ps[ty * 4 + i][c];
            #pragma unroll
            for (int j = 0; j < 4; ++j) vv[j] = Vs[c][tx * 4 + j];
            #pragma unroll
            for (int i = 0; i < 4; ++i)
                #pragma unroll
                for (int j = 0; j < 4; ++j)
                    acc[i][j] = fmaf(pv[i], vv[j], acc[i][j]);
        }
        __syncthreads();
    }

    float* Ob = Obuf + (size_t)b * N_ * C_ + h * HD_;
    #pragma unroll
    for (int i = 0; i < 4; ++i) {
        int r = q0 + ty * 4 + i;
        float inv = 1.f / l_run[ty * 4 + i];
        float4 o;
        o.x = acc[i][0] * inv;
        o.y = acc[i][1] * inv;
        o.z = acc[i][2] * inv;
        o.w = acc[i][3] * inv;
        *(float4*)&Ob[(size_t)r * C_ + tx * 4] = o;
    }
}

// ---------------------------------------------------------------------------
// Kernel 3: output projection, computed transposed so [B,C,N] stores coalesce.
// out[b,co,n] = bo[co] + sum_k A[b,n,k] * Wo[k,co]
// Tile rows = co (64), cols = n (64). grid=(8*16, B)
// ---------------------------------------------------------------------------
__global__ __launch_bounds__(256) void proj_kernel(
    const float* __restrict__ A, const float* __restrict__ Wo,
    const float* __restrict__ bo, float* __restrict__ out)
{
    const int b = blockIdx.y;
    const int tiles_m = N_ / 64;            // 16 token tiles
    const int tc = blockIdx.x / tiles_m;    // co tile 0..7
    const int tm = blockIdx.x % tiles_m;    // token tile 0..15
    const int co0 = tc * 64, m0 = tm * 64;

    __shared__ float As[16][65];   // As[kk][co] from Wo
    __shared__ float Bs[16][65];   // Bs[kk][m]  from attn buffer

    const int tid = threadIdx.x;
    const int tx = tid & 15, ty = tid >> 4;

    float acc[4][4] = {};
    const float* Ab = A + (size_t)b * N_ * C_;

    for (int k0 = 0; k0 < C_; k0 += 16) {
        #pragma unroll
        for (int i = 0; i < 4; ++i) {
            int idx = i * 256 + tid;
            int kk = idx >> 6, co = idx & 63;        // coalesced along co
            As[kk][co] = Wo[(size_t)(k0 + kk) * C_ + co0 + co];
            int m = idx >> 4, kk2 = idx & 15;        // coalesced along kk
            Bs[kk2][m] = Ab[(size_t)(m0 + m) * C_ + k0 + kk2];
        }
        __syncthreads();
        #pragma unroll
        for (int kk = 0; kk < 16; ++kk) {
            float a[4], bb[4];
            #pragma unroll
            for (int i = 0; i < 4; ++i) a[i]  = As[kk][ty * 4 + i];
            #pragma unroll
            for (int j = 0; j < 4; ++j) bb[j] = Bs[kk][tx * 4 + j];
            #pragma unroll
            for (int i = 0; i < 4; ++i)
                #pragma unroll
                for (int j = 0; j < 4; ++j)
                    acc[i][j] = fmaf(a[i], bb[j], acc[i][j]);
        }
        __syncthreads();
    }

    float* ob = out + (size_t)b * C_ * N_;
    #pragma unroll
    for (int i = 0; i < 4; ++i) {
        int co = co0 + ty * 4 + i;
        float bias = bo[co];
        float4 r;
        r.x = acc[i][0] + bias;
        r.y = acc[i][1] + bias;
        r.z = acc[i][2] + bias;
        r.w = acc[i][3] + bias;
        *(float4*)&ob[(size_t)co * N_ + m0 + tx * 4] = r;
    }
}

// ---------------------------------------------------------------------------
extern "C" void kernel_launch(void* const* d_in, const int* in_sizes, int n_in,
                              void* d_out, int out_size, void* d_ws, size_t ws_size,
                              hipStream_t stream) {
    (void)in_sizes; (void)n_in; (void)out_size; (void)ws_size;
    const float* x  = (const float*)d_in[0];
    const float* Wq = (const float*)d_in[1];
    const float* bq = (const float*)d_in[2];
    const float* Wk = (const float*)d_in[3];
    const float* bk = (const float*)d_in[4];
    const float* Wv = (const float*)d_in[5];
    const float* bv = (const float*)d_in[6];
    const float* Wo = (const float*)d_in[7];
    const float* bo = (const float*)d_in[8];
    float* out = (float*)d_out;

    char* ws = (char*)d_ws;
    const size_t buf = (size_t)B_ * N_ * C_ * sizeof(float);  // 32 MiB
    float* Q  = (float*)(ws + 0 * buf);
    float* K  = (float*)(ws + 1 * buf);
    float* V  = (float*)(ws + 2 * buf);
    float* Ab = (float*)(ws + 3 * buf);

    qkv_kernel<<<dim3(128, B_, 3), 256, 0, stream>>>(x, Wq, bq, Wk, bk, Wv, bv, Q, K, V);
    attn_kernel<<<dim3(N_ / 64, NH_, B_), 256, 0, stream>>>(Q, K, V, Ab);
    proj_kernel<<<dim3((C_ / 64) * (N_ / 64), B_), 256, 0, stream>>>(Ab, Wo, bo, out);
}

// Round 2
// 466.499 us; speedup vs baseline: 2.9220x; 2.9220x over previous
//
#include <hip/hip_runtime.h>
#include <hip/hip_bf16.h>
#include <math.h>

// Problem constants
constexpr int B_  = 16;
constexpr int C_  = 512;
constexpr int N_  = 1024;   // 32*32 tokens
constexpr int NH_ = 8;
constexpr int HD_ = 64;

typedef __attribute__((ext_vector_type(8))) short short8;
typedef __attribute__((ext_vector_type(4))) float f32x4;
#define MFMA16(a, b, c) __builtin_amdgcn_mfma_f32_16x16x32_bf16((a), (b), (c), 0, 0, 0)

__device__ __forceinline__ short f2bf(float f) {
    union { float f; unsigned u; } a; a.f = f;
    unsigned r = a.u + 0x7fffu + ((a.u >> 16) & 1u);   // RNE
    return (short)(r >> 16);
}
__device__ __forceinline__ float bf2f(short s) {
    union { unsigned u; float f; } a; a.u = ((unsigned)(unsigned short)s) << 16;
    return a.f;
}

// ---------------------------------------------------------------------------
// prep_x: x[b][c][n] f32 -> xt[b][n][c] bf16   (64x64 tiles via LDS)
// ---------------------------------------------------------------------------
__global__ __launch_bounds__(256) void prep_x(const float* __restrict__ x,
                                              short* __restrict__ xt) {
    const int b  = blockIdx.y;
    const int tn = blockIdx.x / (C_ / 64);   // token tile 0..15
    const int tc = blockIdx.x % (C_ / 64);   // channel tile 0..7
    __shared__ float t[64][65];
    const int tid = threadIdx.x;
    #pragma unroll
    for (int i = 0; i < 16; ++i) {
        int idx = i * 256 + tid;              // 0..4095
        int r = idx >> 6, col = idx & 63;     // r = c-offset, col = n-offset
        t[r][col] = x[((size_t)b * C_ + tc * 64 + r) * N_ + tn * 64 + col];
    }
    __syncthreads();
    #pragma unroll
    for (int i = 0; i < 16; ++i) {
        int idx = i * 256 + tid;
        int r2 = idx >> 6, col2 = idx & 63;   // r2 = n-offset, col2 = c-offset
        xt[((size_t)b * N_ + tn * 64 + r2) * C_ + tc * 64 + col2] = f2bf(t[col2][r2]);
    }
}

// ---------------------------------------------------------------------------
// prep_w: W[c][co] f32 -> WT[co][c] bf16, 4 matrices via blockIdx.y
// ---------------------------------------------------------------------------
__global__ __launch_bounds__(256) void prep_w(
    const float* __restrict__ Wq, const float* __restrict__ Wk,
    const float* __restrict__ Wv, const float* __restrict__ Wo,
    short* __restrict__ WqT, short* __restrict__ WkT,
    short* __restrict__ WvT, short* __restrict__ WoT) {
    const int z = blockIdx.y;
    const float* W = (z == 0) ? Wq : (z == 1) ? Wk : (z == 2) ? Wv : Wo;
    short* WT      = (z == 0) ? WqT : (z == 1) ? WkT : (z == 2) ? WvT : WoT;
    const int tco = blockIdx.x / (C_ / 64);
    const int tc  = blockIdx.x % (C_ / 64);
    __shared__ float t[64][65];
    const int tid = threadIdx.x;
    #pragma unroll
    for (int i = 0; i < 16; ++i) {
        int idx = i * 256 + tid;
        int r = idx >> 6, col = idx & 63;     // r = c-offset, col = co-offset
        t[r][col] = W[((size_t)tc * 64 + r) * C_ + tco * 64 + col];
    }
    __syncthreads();
    #pragma unroll
    for (int i = 0; i < 16; ++i) {
        int idx = i * 256 + tid;
        int r2 = idx >> 6, col2 = idx & 63;   // r2 = co-offset, col2 = c-offset
        WT[((size_t)tco * 64 + r2) * C_ + tc * 64 + col2] = f2bf(t[col2][r2]);
    }
}

// ---------------------------------------------------------------------------
// qkv_mfma: Y = xf @ W + b, plain bf16 MFMA.
// Outputs: z=0 -> Qh/Ql (split, pre-scaled by 0.125), z=1 -> Kb bf16,
//          z=2 -> Vt bf16 transposed to [b,h,hd,key] (via per-wave LDS).
// Block tile 128 tok x 64 co, 4 waves (2x2), wave tile 64x32. BK=32.
// ---------------------------------------------------------------------------
__global__ __launch_bounds__(256) void qkv_mfma(
    const short* __restrict__ xt,
    const short* __restrict__ WqT, const float* __restrict__ bq,
    const short* __restrict__ WkT, const float* __restrict__ bk,
    const short* __restrict__ WvT, const float* __restrict__ bv,
    short* __restrict__ Qh, short* __restrict__ Ql,
    short* __restrict__ Kb, short* __restrict__ Vt) {
    const int b = blockIdx.y, z = blockIdx.z;
    const int mt = blockIdx.x >> 3;   // 0..7 token tile
    const int nt = blockIdx.x & 7;    // 0..7 cout tile
    const int tid = threadIdx.x;
    const int wave = tid >> 6, lane = tid & 63;
    const int g = lane >> 4, c = lane & 15;
    const int wm = wave >> 1, wn = wave & 1;
    const int tok0 = mt * 128 + wm * 64;
    const int co0  = nt * 64 + wn * 32;

    const short* W    = (z == 0) ? WqT : (z == 1) ? WkT : WvT;
    const float* bias = (z == 0) ? bq  : (z == 1) ? bk  : bv;

    f32x4 acc[4][2] = {};
    const short* xb = xt + (size_t)b * N_ * C_;

    for (int k0 = 0; k0 < C_; k0 += 32) {
        short8 bf[2];
        #pragma unroll
        for (int fn = 0; fn < 2; ++fn)
            bf[fn] = *(const short8*)&W[((size_t)(co0 + fn * 16 + c)) * C_ + k0 + g * 8];
        #pragma unroll
        for (int fm = 0; fm < 4; ++fm) {
            short8 af = *(const short8*)&xb[((size_t)(tok0 + fm * 16 + c)) * C_ + k0 + g * 8];
            acc[fm][0] = MFMA16(af, bf[0], acc[fm][0]);
            acc[fm][1] = MFMA16(af, bf[1], acc[fm][1]);
        }
    }

    if (z < 2) {  // Q (split + 0.125 scale) or K (plain bf16), layout [b,h,tok,hd]
        #pragma unroll
        for (int fm = 0; fm < 4; ++fm)
            #pragma unroll
            for (int fn = 0; fn < 2; ++fn)
                #pragma unroll
                for (int r = 0; r < 4; ++r) {
                    int tok = tok0 + fm * 16 + 4 * g + r;
                    int co  = co0 + fn * 16 + c;
                    float v = acc[fm][fn][r] + bias[co];
                    int h = co >> 6, hd = co & 63;
                    size_t off = (((size_t)(b * NH_ + h)) * N_ + tok) * HD_ + hd;
                    if (z == 0) {
                        v *= 0.125f;                 // fold 1/sqrt(HD) into Q
                        short hi = f2bf(v);
                        Qh[off] = hi;
                        Ql[off] = f2bf(v - bf2f(hi));
                    } else {
                        Kb[off] = f2bf(v);
                    }
                }
    } else {      // V: transpose wave tile (64 tok x 32 co) -> Vt[b,h,hd,key]
        __shared__ short tr[4][32][72];
        short (*t)[72] = tr[wave];
        #pragma unroll
        for (int fm = 0; fm < 4; ++fm)
            #pragma unroll
            for (int fn = 0; fn < 2; ++fn)
                #pragma unroll
                for (int r = 0; r < 4; ++r) {
                    int co = co0 + fn * 16 + c;
                    float v = acc[fm][fn][r] + bias[co];
                    t[fn * 16 + c][fm * 16 + 4 * g + r] = f2bf(v);
                }
        // per-wave private buffer: compiler inserts lgkmcnt; no barrier needed
        int row = lane >> 1, half = lane & 1;     // row = co-offset 0..31
        int co = co0 + row;
        int h = co >> 6, hd = co & 63;
        size_t base = (((size_t)(b * NH_ + h)) * HD_ + hd) * N_ + tok0 + half * 32;
        #pragma unroll
        for (int j = 0; j < 4; ++j) {
            short8 v = *(const short8*)&t[row][half * 32 + j * 8];
            *(short8*)&Vt[base + j * 8] = v;
        }
    }
}

// ---------------------------------------------------------------------------
// attn_mfma: flash attention, swapped-QK^T (S^T = K . Q^T) so softmax is
// lane-local. Per block: 64 q-rows (4 waves x 16), iterate 16 KV chunks of 64.
// QK^T: 2-term split Q (Qh+Ql). PV: plain bf16 via per-wave LDS P buffer.
// K/V read directly from global (L2/L3-resident) - no staging, no barriers.
// Output: attnout split hi/lo bf16, layout [b, tok, c].
// ---------------------------------------------------------------------------
__global__ __launch_bounds__(256) void attn_mfma(
    const short* __restrict__ Qh, const short* __restrict__ Ql,
    const short* __restrict__ Kb, const short* __restrict__ Vt,
    short* __restrict__ Ah, short* __restrict__ Al) {
    const int qt = blockIdx.x;        // 0..15
    const int h  = blockIdx.y, b = blockIdx.z;
    const int tid = threadIdx.x;
    const int wave = tid >> 6, lane = tid & 63;
    const int g = lane >> 4, c = lane & 15;
    const int q0 = qt * 64 + wave * 16;          // wave's 16 q rows
    const size_t bh = (size_t)(b * NH_ + h);

    const short* Qhb = Qh + (bh * N_ + q0) * HD_;
    const short* Qlb = Ql + (bh * N_ + q0) * HD_;
    const short* Kbb = Kb + bh * N_ * HD_;
    const short* Vtb = Vt + bh * HD_ * N_;

    __shared__ short Pl[4][16][80];              // per-wave P buffer (16q x 64key, pad 80)
    short (*P)[80] = Pl[wave];

    short8 qh[2], ql[2];
    #pragma unroll
    for (int k0 = 0; k0 < 2; ++k0) {
        qh[k0] = *(const short8*)&Qhb[c * HD_ + k0 * 32 + g * 8];
        ql[k0] = *(const short8*)&Qlb[c * HD_ + k0 * 32 + g * 8];
    }

    f32x4 o[4] = {};
    float m_run = -1e30f, l_run = 0.f;

    for (int key0 = 0; key0 < N_; key0 += 64) {
        // S^T[key][q] for this wave's 16 q, 64 keys: 4 key-subtiles
        f32x4 s[4] = {};
        #pragma unroll
        for (int m = 0; m < 4; ++m)
            #pragma unroll
            for (int k0 = 0; k0 < 2; ++k0) {
                short8 kf = *(const short8*)&Kbb[((size_t)(key0 + m * 16 + c)) * HD_ + k0 * 32 + g * 8];
                s[m] = MFMA16(kf, qh[k0], s[m]);
                s[m] = MFMA16(kf, ql[k0], s[m]);
            }
        // lane holds S[q = q0+c][key = key0 + m*16 + 4g + r] -> lane-local softmax
        float cmax = -1e30f;
        #pragma unroll
        for (int m = 0; m < 4; ++m)
            #pragma unroll
            for (int r = 0; r < 4; ++r) cmax = fmaxf(cmax, s[m][r]);
        cmax = fmaxf(cmax, __shfl_xor(cmax, 16));
        cmax = fmaxf(cmax, __shfl_xor(cmax, 32));
        float m_new = fmaxf(m_run, cmax);
        float corr = __expf(m_run - m_new);
        float p[4][4];
        float lsum = 0.f;
        #pragma unroll
        for (int m = 0; m < 4; ++m)
            #pragma unroll
            for (int r = 0; r < 4; ++r) {
                p[m][r] = __expf(s[m][r] - m_new);
                lsum += p[m][r];
            }
        lsum += __shfl_xor(lsum, 16);
        lsum += __shfl_xor(lsum, 32);
        l_run = l_run * corr + lsum;
        m_run = m_new;
        // write P[q][key] (bf16 pairs)
        #pragma unroll
        for (int m = 0; m < 4; ++m) {
            unsigned u0 = (unsigned)(unsigned short)f2bf(p[m][0]) |
                          ((unsigned)(unsigned short)f2bf(p[m][1]) << 16);
            unsigned u1 = (unsigned)(unsigned short)f2bf(p[m][2]) |
                          ((unsigned)(unsigned short)f2bf(p[m][3]) << 16);
            *(unsigned*)&P[c][m * 16 + 4 * g]     = u0;
            *(unsigned*)&P[c][m * 16 + 4 * g + 2] = u1;
        }
        // rescale O (rows q' = 4g+r need stats from lane q'=c)
        float corr_r[4];
        #pragma unroll
        for (int r = 0; r < 4; ++r) corr_r[r] = __shfl(corr, 4 * g + r);
        #pragma unroll
        for (int n = 0; n < 4; ++n)
            #pragma unroll
            for (int r = 0; r < 4; ++r) o[n][r] *= corr_r[r];
        // PV: O[q][hd] += P[16q x 64key] . V[64key x 64hd]
        #pragma unroll
        for (int k0 = 0; k0 < 2; ++k0) {
            short8 pa = *(const short8*)&P[c][k0 * 32 + g * 8];
            #pragma unroll
            for (int n = 0; n < 4; ++n) {
                short8 vf = *(const short8*)&Vtb[((size_t)(n * 16 + c)) * N_ + key0 + k0 * 32 + g * 8];
                o[n] = MFMA16(pa, vf, o[n]);
            }
        }
    }

    // epilogue: divide by l, split hi/lo, store [b, tok, c]
    float li[4];
    #pragma unroll
    for (int r = 0; r < 4; ++r) li[r] = 1.f / __shfl(l_run, 4 * g + r);
    #pragma unroll
    for (int n = 0; n < 4; ++n)
        #pragma unroll
        for (int r = 0; r < 4; ++r) {
            int tok = q0 + 4 * g + r;
            int cc  = h * 64 + n * 16 + c;
            float v = o[n][r] * li[r];
            size_t off = ((size_t)b * N_ + tok) * C_ + cc;
            short hi = f2bf(v);
            Ah[off] = hi;
            Al[off] = f2bf(v - bf2f(hi));
        }
}

// ---------------------------------------------------------------------------
// proj_mfma: out[b,co,n] = bo[co] + sum_k A[tok][k] Wo[k][co],
// A = Ah + Al (2-term split). Epilogue transposes wave tile via LDS so the
// [B,C,N] f32 stores are coalesced.
// ---------------------------------------------------------------------------
__global__ __launch_bounds__(256) void proj_mfma(
    const short* __restrict__ Ah, const short* __restrict__ Al,
    const short* __restrict__ WoT, const float* __restrict__ bo,
    float* __restrict__ out) {
    const int b = blockIdx.y;
    const int mt = blockIdx.x >> 3;
    const int nt = blockIdx.x & 7;
    const int tid = threadIdx.x;
    const int wave = tid >> 6, lane = tid & 63;
    const int g = lane >> 4, c = lane & 15;
    const int wm = wave >> 1, wn = wave & 1;
    const int tok0 = mt * 128 + wm * 64;
    const int co0  = nt * 64 + wn * 32;

    f32x4 acc[4][2] = {};
    const short* Ahb = Ah + (size_t)b * N_ * C_;
    const short* Alb = Al + (size_t)b * N_ * C_;

    for (int k0 = 0; k0 < C_; k0 += 32) {
        short8 bf[2];
        #pragma unroll
        for (int fn = 0; fn < 2; ++fn)
            bf[fn] = *(const short8*)&WoT[((size_t)(co0 + fn * 16 + c)) * C_ + k0 + g * 8];
        #pragma unroll
        for (int fm = 0; fm < 4; ++fm) {
            short8 ah = *(const short8*)&Ahb[((size_t)(tok0 + fm * 16 + c)) * C_ + k0 + g * 8];
            short8 al = *(const short8*)&Alb[((size_t)(tok0 + fm * 16 + c)) * C_ + k0 + g * 8];
            #pragma unroll
            for (int fn = 0; fn < 2; ++fn) {
                acc[fm][fn] = MFMA16(al, bf[fn], acc[fm][fn]);
                acc[fm][fn] = MFMA16(ah, bf[fn], acc[fm][fn]);
            }
        }
    }

    // transpose wave tile (64 tok x 32 co) via LDS -> coalesced out stores
    __shared__ float tr[4][32][68];
    float (*t)[68] = tr[wave];
    #pragma unroll
    for (int fm = 0; fm < 4; ++fm)
        #pragma unroll
        for (int fn = 0; fn < 2; ++fn) {
            float4 v = *(float4*)&acc[fm][fn];
            *(float4*)&t[fn * 16 + c][fm * 16 + 4 * g] = v;
        }
    // per-wave private; compiler orders via lgkmcnt
    int row = lane >> 1, half = lane & 1;        // row = co-offset 0..31
    int co = co0 + row;
    float bias = bo[co];
    float* ob = out + ((size_t)b * C_ + co) * N_ + tok0 + half * 32;
    #pragma unroll
    for (int j = 0; j < 8; ++j) {
        float4 v = *(const float4*)&t[row][half * 32 + j * 4];
        v.x += bias; v.y += bias; v.z += bias; v.w += bias;
        *(float4*)&ob[j * 4] = v;
    }
}

// ---------------------------------------------------------------------------
extern "C" void kernel_launch(void* const* d_in, const int* in_sizes, int n_in,
                              void* d_out, int out_size, void* d_ws, size_t ws_size,
                              hipStream_t stream) {
    (void)in_sizes; (void)n_in; (void)out_size; (void)ws_size;
    const float* x  = (const float*)d_in[0];
    const float* Wq = (const float*)d_in[1];
    const float* bq = (const float*)d_in[2];
    const float* Wk = (const float*)d_in[3];
    const float* bk = (const float*)d_in[4];
    const float* Wv = (const float*)d_in[5];
    const float* bv = (const float*)d_in[6];
    const float* Wo = (const float*)d_in[7];
    const float* bo = (const float*)d_in[8];
    float* out = (float*)d_out;

    char* ws = (char*)d_ws;
    const size_t MB = 1024 * 1024;
    short* xt  = (short*)(ws + 0 * MB);      // 16 MB bf16 [b,n,c]
    short* WqT = (short*)(ws + 16 * MB);     // 0.5 MB each
    short* WkT = (short*)(ws + 16 * MB + 512 * 1024);
    short* WvT = (short*)(ws + 17 * MB);
    short* WoT = (short*)(ws + 17 * MB + 512 * 1024);
    short* Qh  = (short*)(ws + 18 * MB);     // 16 MB [b,h,q,hd]
    short* Ql  = (short*)(ws + 34 * MB);
    short* Kb  = (short*)(ws + 50 * MB);
    short* Vt  = (short*)(ws + 66 * MB);     // 16 MB [b,h,hd,key]
    short* Ah  = (short*)(ws + 82 * MB);     // 16 MB [b,tok,c]
    short* Al  = (short*)(ws + 98 * MB);     // total 114 MB

    prep_x<<<dim3(128, B_), 256, 0, stream>>>(x, xt);
    prep_w<<<dim3(64, 4), 256, 0, stream>>>(Wq, Wk, Wv, Wo, WqT, WkT, WvT, WoT);
    qkv_mfma<<<dim3(64, B_, 3), 256, 0, stream>>>(xt, WqT, bq, WkT, bk, WvT, bv,
                                                  Qh, Ql, Kb, Vt);
    attn_mfma<<<dim3(16, NH_, B_), 256, 0, stream>>>(Qh, Ql, Kb, Vt, Ah, Al);
    proj_mfma<<<dim3(64, B_), 256, 0, stream>>>(Ah, Al, WoT, bo, out);
}

// Round 3
// 291.028 us; speedup vs baseline: 4.6838x; 1.6029x over previous
//
#include <hip/hip_runtime.h>
#include <hip/hip_bf16.h>
#include <math.h>

// Problem constants
constexpr int B_  = 16;
constexpr int C_  = 512;
constexpr int N_  = 1024;   // 32*32 tokens
constexpr int NH_ = 8;
constexpr int HD_ = 64;

// 1/sqrt(64) * log2(e): softmax computed in exp2 domain
#define QSCALE 0.18033688f

typedef __attribute__((ext_vector_type(8))) short short8;
typedef __attribute__((ext_vector_type(4))) short short4v;
typedef __attribute__((ext_vector_type(4))) float f32x4;
#define MFMA16(a, b, c) __builtin_amdgcn_mfma_f32_16x16x32_bf16((a), (b), (c), 0, 0, 0)

#if __has_builtin(__builtin_amdgcn_exp2f)
#define EXP2(x) __builtin_amdgcn_exp2f(x)
#else
#define EXP2(x) exp2f(x)
#endif

__device__ __forceinline__ short f2bf(float f) {          // manual RNE (prep kernels)
    union { float f; unsigned u; } a; a.f = f;
    unsigned r = a.u + 0x7fffu + ((a.u >> 16) & 1u);
    return (short)(r >> 16);
}
__device__ __forceinline__ short f2bf_hw(float f) {       // hardware cvt (hot paths)
    __hip_bfloat16 h = __float2bfloat16(f);
    return *reinterpret_cast<short*>(&h);
}

// ---------------------------------------------------------------------------
// prep_x: x[b][c][n] f32 -> xt[b][n][c] bf16   (64x64 tiles via LDS)
// ---------------------------------------------------------------------------
__global__ __launch_bounds__(256) void prep_x(const float* __restrict__ x,
                                              short* __restrict__ xt) {
    const int b  = blockIdx.y;
    const int tn = blockIdx.x / (C_ / 64);
    const int tc = blockIdx.x % (C_ / 64);
    __shared__ float t[64][65];
    const int tid = threadIdx.x;
    #pragma unroll
    for (int i = 0; i < 16; ++i) {
        int idx = i * 256 + tid;
        int r = idx >> 6, col = idx & 63;
        t[r][col] = x[((size_t)b * C_ + tc * 64 + r) * N_ + tn * 64 + col];
    }
    __syncthreads();
    #pragma unroll
    for (int i = 0; i < 16; ++i) {
        int idx = i * 256 + tid;
        int r2 = idx >> 6, col2 = idx & 63;
        xt[((size_t)b * N_ + tn * 64 + r2) * C_ + tc * 64 + col2] = f2bf(t[col2][r2]);
    }
}

// ---------------------------------------------------------------------------
// prep_w: W[c][co] f32 -> WT[co][c] bf16, 4 matrices via blockIdx.y
// ---------------------------------------------------------------------------
__global__ __launch_bounds__(256) void prep_w(
    const float* __restrict__ Wq, const float* __restrict__ Wk,
    const float* __restrict__ Wv, const float* __restrict__ Wo,
    short* __restrict__ WqT, short* __restrict__ WkT,
    short* __restrict__ WvT, short* __restrict__ WoT) {
    const int z = blockIdx.y;
    const float* W = (z == 0) ? Wq : (z == 1) ? Wk : (z == 2) ? Wv : Wo;
    short* WT      = (z == 0) ? WqT : (z == 1) ? WkT : (z == 2) ? WvT : WoT;
    const int tco = blockIdx.x / (C_ / 64);
    const int tc  = blockIdx.x % (C_ / 64);
    __shared__ float t[64][65];
    const int tid = threadIdx.x;
    #pragma unroll
    for (int i = 0; i < 16; ++i) {
        int idx = i * 256 + tid;
        int r = idx >> 6, col = idx & 63;
        t[r][col] = W[((size_t)tc * 64 + r) * C_ + tco * 64 + col];
    }
    __syncthreads();
    #pragma unroll
    for (int i = 0; i < 16; ++i) {
        int idx = i * 256 + tid;
        int r2 = idx >> 6, col2 = idx & 63;
        WT[((size_t)tco * 64 + r2) * C_ + tc * 64 + col2] = f2bf(t[col2][r2]);
    }
}

// ---------------------------------------------------------------------------
// qkv_mfma: Y = xf @ W + b, bf16 MFMA. Block 128x128, 4 waves (2x2),
// wave tile 64x64 (16 MFMA : 8 loads per BK=32 step).
// z=0 -> Qs (scaled by QSCALE), z=1 -> Kb, both [b,h,tok,hd];
// z=2 -> Vt transposed to [b,h,hd,key] via per-wave LDS (two passes).
// ---------------------------------------------------------------------------
__global__ __launch_bounds__(256) void qkv_mfma(
    const short* __restrict__ xt,
    const short* __restrict__ WqT, const float* __restrict__ bq,
    const short* __restrict__ WkT, const float* __restrict__ bk,
    const short* __restrict__ WvT, const float* __restrict__ bv,
    short* __restrict__ Qs, short* __restrict__ Kb, short* __restrict__ Vt) {
    const int b = blockIdx.y, z = blockIdx.z;
    const int mt = blockIdx.x >> 2;   // 0..7 token tile (128 wide)
    const int nt = blockIdx.x & 3;    // 0..3 cout tile (128 wide)
    const int tid = threadIdx.x;
    const int wave = tid >> 6, lane = tid & 63;
    const int g = lane >> 4, c = lane & 15;
    const int wm = wave >> 1, wn = wave & 1;
    const int tok0 = mt * 128 + wm * 64;
    const int co0  = nt * 128 + wn * 64;

    const short* W    = (z == 0) ? WqT : (z == 1) ? WkT : WvT;
    const float* bias = (z == 0) ? bq  : (z == 1) ? bk  : bv;

    f32x4 acc[4][4] = {};
    const short* xb = xt + (size_t)b * N_ * C_;

    for (int k0 = 0; k0 < C_; k0 += 32) {
        short8 bf[4], af[4];
        #pragma unroll
        for (int fn = 0; fn < 4; ++fn)
            bf[fn] = *(const short8*)&W[((size_t)(co0 + fn * 16 + c)) * C_ + k0 + g * 8];
        #pragma unroll
        for (int fm = 0; fm < 4; ++fm)
            af[fm] = *(const short8*)&xb[((size_t)(tok0 + fm * 16 + c)) * C_ + k0 + g * 8];
        #pragma unroll
        for (int fm = 0; fm < 4; ++fm)
            #pragma unroll
            for (int fn = 0; fn < 4; ++fn)
                acc[fm][fn] = MFMA16(af[fm], bf[fn], acc[fm][fn]);
    }

    const int h = co0 >> 6;                 // co0 is 64-aligned
    const size_t bh = (size_t)(b * NH_ + h);

    if (z < 2) {
        short* Y = (z == 0) ? Qs : Kb;
        const float sc = (z == 0) ? QSCALE : 1.f;
        #pragma unroll
        for (int fm = 0; fm < 4; ++fm)
            #pragma unroll
            for (int fn = 0; fn < 4; ++fn)
                #pragma unroll
                for (int r = 0; r < 4; ++r) {
                    int tok = tok0 + fm * 16 + 4 * g + r;
                    int hd  = fn * 16 + c;
                    float v = (acc[fm][fn][r] + bias[co0 + hd]) * sc;
                    Y[(bh * N_ + tok) * HD_ + hd] = f2bf_hw(v);
                }
    } else {
        __shared__ short tr[4][32][72];
        short (*t)[72] = tr[wave];
        #pragma unroll
        for (int p = 0; p < 2; ++p) {       // two 32-row passes (in-order DS per wave)
            #pragma unroll
            for (int fn2 = 0; fn2 < 2; ++fn2) {
                int fnn = 2 * p + fn2;
                #pragma unroll
                for (int fm = 0; fm < 4; ++fm) {
                    short4v pk;
                    #pragma unroll
                    for (int r = 0; r < 4; ++r)
                        pk[r] = f2bf_hw(acc[fm][fnn][r] + bias[co0 + fnn * 16 + c]);
                    *(short4v*)&t[fn2 * 16 + c][fm * 16 + 4 * g] = pk;
                }
            }
            int row = lane >> 1, half2 = lane & 1;
            int hd = p * 32 + row;
            size_t base = (bh * HD_ + hd) * N_ + tok0 + half2 * 32;
            #pragma unroll
            for (int j = 0; j < 4; ++j)
                *(short8*)&Vt[base + j * 8] = *(const short8*)&t[row][half2 * 32 + j * 8];
        }
    }
}

// ---------------------------------------------------------------------------
// attn_mfma: flash attention, swapped QK^T (S^T = K.Q^T) -> lane-local softmax.
// 4 waves x 32 q-rows = 128 q per block; 16 KV chunks of 64 keys.
// K-next prefetch after QK^T; V prefetch before softmax; exp2-domain softmax
// with defer-max (thr=8); per-wave LDS P buffer; no barriers at all.
// ---------------------------------------------------------------------------
__global__ __launch_bounds__(256) void attn_mfma(
    const short* __restrict__ Qs, const short* __restrict__ Kb,
    const short* __restrict__ Vt, short* __restrict__ Ah) {
    const int qt = blockIdx.x;        // 0..7
    const int h  = blockIdx.y, b = blockIdx.z;
    const int tid = threadIdx.x;
    const int wave = tid >> 6, lane = tid & 63;
    const int g = lane >> 4, c = lane & 15;
    const int q0 = qt * 128 + wave * 32;         // wave's 32 q rows
    const size_t bh = (size_t)(b * NH_ + h);

    const short* Qw  = Qs + (bh * N_ + q0) * HD_;
    const short* Kbb = Kb + bh * N_ * HD_;
    const short* Vtb = Vt + bh * HD_ * N_;

    __shared__ short Pl[4][32][72];              // per-wave P buffer
    short (*P)[72] = Pl[wave];

    short8 qf[2][2];
    #pragma unroll
    for (int f = 0; f < 2; ++f)
        #pragma unroll
        for (int k0 = 0; k0 < 2; ++k0)
            qf[f][k0] = *(const short8*)&Qw[(f * 16 + c) * HD_ + k0 * 32 + g * 8];

    f32x4 o[2][4] = {};
    float m_run[2] = {-1e30f, -1e30f}, l_run[2] = {0.f, 0.f};

    // prefetch K chunk 0
    short8 kf[4][2];
    #pragma unroll
    for (int m = 0; m < 4; ++m)
        #pragma unroll
        for (int k0 = 0; k0 < 2; ++k0)
            kf[m][k0] = *(const short8*)&Kbb[((size_t)(m * 16 + c)) * HD_ + k0 * 32 + g * 8];

    for (int it = 0; it < 16; ++it) {
        const int key0 = it * 64;
        f32x4 s[2][4] = {};
        __builtin_amdgcn_s_setprio(1);
        #pragma unroll
        for (int m = 0; m < 4; ++m)
            #pragma unroll
            for (int k0 = 0; k0 < 2; ++k0) {
                s[0][m] = MFMA16(kf[m][k0], qf[0][k0], s[0][m]);
                s[1][m] = MFMA16(kf[m][k0], qf[1][k0], s[1][m]);
            }
        __builtin_amdgcn_s_setprio(0);

        // prefetch this chunk's V and next chunk's K (kf dead after QK^T)
        short8 vf[4][2];
        #pragma unroll
        for (int n = 0; n < 4; ++n)
            #pragma unroll
            for (int k0 = 0; k0 < 2; ++k0)
                vf[n][k0] = *(const short8*)&Vtb[((size_t)(n * 16 + c)) * N_ + key0 + k0 * 32 + g * 8];
        const int keyn = (it < 15) ? key0 + 64 : key0;   // clamped (redundant last iter)
        #pragma unroll
        for (int m = 0; m < 4; ++m)
            #pragma unroll
            for (int k0 = 0; k0 < 2; ++k0)
                kf[m][k0] = *(const short8*)&Kbb[((size_t)(keyn + m * 16 + c)) * HD_ + k0 * 32 + g * 8];

        // softmax (exp2 domain) per fragment
        #pragma unroll
        for (int f = 0; f < 2; ++f) {
            float cmax = -1e30f;
            #pragma unroll
            for (int m = 0; m < 4; ++m)
                #pragma unroll
                for (int r = 0; r < 4; ++r) cmax = fmaxf(cmax, s[f][m][r]);
            cmax = fmaxf(cmax, __shfl_xor(cmax, 16));
            cmax = fmaxf(cmax, __shfl_xor(cmax, 32));
            const int need = __any(cmax > m_run[f] + 8.f);
            const float m_new = need ? fmaxf(m_run[f], cmax) : m_run[f];
            float lsum = 0.f;
            #pragma unroll
            for (int m = 0; m < 4; ++m)
                #pragma unroll
                for (int r = 0; r < 4; ++r) {
                    float p = EXP2(s[f][m][r] - m_new);
                    s[f][m][r] = p;
                    lsum += p;
                }
            lsum += __shfl_xor(lsum, 16);
            lsum += __shfl_xor(lsum, 32);
            if (need) {
                float corr = EXP2(m_run[f] - m_new);
                l_run[f] = l_run[f] * corr + lsum;
                m_run[f] = m_new;
                float cr[4];
                #pragma unroll
                for (int r = 0; r < 4; ++r) cr[r] = __shfl(corr, 4 * g + r);
                #pragma unroll
                for (int n = 0; n < 4; ++n)
                    #pragma unroll
                    for (int r = 0; r < 4; ++r) o[f][n][r] *= cr[r];
            } else {
                l_run[f] += lsum;
            }
            // pack P (bf16) into per-wave LDS
            #pragma unroll
            for (int m = 0; m < 4; ++m) {
                short4v pk;
                #pragma unroll
                for (int r = 0; r < 4; ++r) pk[r] = f2bf_hw(s[f][m][r]);
                *(short4v*)&P[f * 16 + c][m * 16 + 4 * g] = pk;
            }
        }

        // PV
        __builtin_amdgcn_s_setprio(1);
        #pragma unroll
        for (int f = 0; f < 2; ++f)
            #pragma unroll
            for (int k0 = 0; k0 < 2; ++k0) {
                short8 pa = *(const short8*)&P[f * 16 + c][k0 * 32 + g * 8];
                #pragma unroll
                for (int n = 0; n < 4; ++n)
                    o[f][n] = MFMA16(pa, vf[n][k0], o[f][n]);
            }
        __builtin_amdgcn_s_setprio(0);
    }

    // epilogue: divide by l, store bf16 [b, tok, c]
    #pragma unroll
    for (int f = 0; f < 2; ++f) {
        float li[4];
        #pragma unroll
        for (int r = 0; r < 4; ++r) li[r] = 1.f / __shfl(l_run[f], 4 * g + r);
        #pragma unroll
        for (int n = 0; n < 4; ++n)
            #pragma unroll
            for (int r = 0; r < 4; ++r) {
                int tok = q0 + f * 16 + 4 * g + r;
                int cc  = h * 64 + n * 16 + c;
                Ah[((size_t)b * N_ + tok) * C_ + cc] = f2bf_hw(o[f][n][r] * li[r]);
            }
    }
}

// ---------------------------------------------------------------------------
// proj_mfma: out[b,co,n] = bo[co] + sum_k A[tok][k] Wo[k][co], A bf16.
// Block 128 tok x 64 co, wave 64x32. Epilogue transposes via LDS so the
// [B,C,N] f32 stores are coalesced.
// ---------------------------------------------------------------------------
__global__ __launch_bounds__(256) void proj_mfma(
    const short* __restrict__ Ah, const short* __restrict__ WoT,
    const float* __restrict__ bo, float* __restrict__ out) {
    const int b = blockIdx.y;
    const int mt = blockIdx.x >> 3;
    const int nt = blockIdx.x & 7;
    const int tid = threadIdx.x;
    const int wave = tid >> 6, lane = tid & 63;
    const int g = lane >> 4, c = lane & 15;
    const int wm = wave >> 1, wn = wave & 1;
    const int tok0 = mt * 128 + wm * 64;
    const int co0  = nt * 64 + wn * 32;

    f32x4 acc[4][2] = {};
    const short* Ab = Ah + (size_t)b * N_ * C_;

    for (int k0 = 0; k0 < C_; k0 += 32) {
        short8 bf[2];
        #pragma unroll
        for (int fn = 0; fn < 2; ++fn)
            bf[fn] = *(const short8*)&WoT[((size_t)(co0 + fn * 16 + c)) * C_ + k0 + g * 8];
        #pragma unroll
        for (int fm = 0; fm < 4; ++fm) {
            short8 af = *(const short8*)&Ab[((size_t)(tok0 + fm * 16 + c)) * C_ + k0 + g * 8];
            acc[fm][0] = MFMA16(af, bf[0], acc[fm][0]);
            acc[fm][1] = MFMA16(af, bf[1], acc[fm][1]);
        }
    }

    __shared__ float tr[4][32][68];
    float (*t)[68] = tr[wave];
    #pragma unroll
    for (int fm = 0; fm < 4; ++fm)
        #pragma unroll
        for (int fn = 0; fn < 2; ++fn) {
            float4 v = *(float4*)&acc[fm][fn];
            *(float4*)&t[fn * 16 + c][fm * 16 + 4 * g] = v;
        }
    int row = lane >> 1, half = lane & 1;
    int co = co0 + row;
    float bias = bo[co];
    float* ob = out + ((size_t)b * C_ + co) * N_ + tok0 + half * 32;
    #pragma unroll
    for (int j = 0; j < 8; ++j) {
        float4 v = *(const float4*)&t[row][half * 32 + j * 4];
        v.x += bias; v.y += bias; v.z += bias; v.w += bias;
        *(float4*)&ob[j * 4] = v;
    }
}

// ---------------------------------------------------------------------------
extern "C" void kernel_launch(void* const* d_in, const int* in_sizes, int n_in,
                              void* d_out, int out_size, void* d_ws, size_t ws_size,
                              hipStream_t stream) {
    (void)in_sizes; (void)n_in; (void)out_size; (void)ws_size;
    const float* x  = (const float*)d_in[0];
    const float* Wq = (const float*)d_in[1];
    const float* bq = (const float*)d_in[2];
    const float* Wk = (const float*)d_in[3];
    const float* bk = (const float*)d_in[4];
    const float* Wv = (const float*)d_in[5];
    const float* bv = (const float*)d_in[6];
    const float* Wo = (const float*)d_in[7];
    const float* bo = (const float*)d_in[8];
    float* out = (float*)d_out;

    char* ws = (char*)d_ws;
    const size_t MB = 1024 * 1024;
    short* xt  = (short*)(ws + 0 * MB);      // 16 MB bf16 [b,n,c]
    short* WqT = (short*)(ws + 16 * MB);
    short* WkT = (short*)(ws + 16 * MB + 512 * 1024);
    short* WvT = (short*)(ws + 17 * MB);
    short* WoT = (short*)(ws + 17 * MB + 512 * 1024);
    short* Qsb = (short*)(ws + 18 * MB);     // 16 MB [b,h,q,hd]
    short* Kb  = (short*)(ws + 34 * MB);     // 16 MB [b,h,k,hd]
    short* Vt  = (short*)(ws + 50 * MB);     // 16 MB [b,h,hd,k]
    short* Ah  = (short*)(ws + 66 * MB);     // 16 MB [b,tok,c]

    prep_x<<<dim3(128, B_), 256, 0, stream>>>(x, xt);
    prep_w<<<dim3(64, 4), 256, 0, stream>>>(Wq, Wk, Wv, Wo, WqT, WkT, WvT, WoT);
    qkv_mfma<<<dim3(32, B_, 3), 256, 0, stream>>>(xt, WqT, bq, WkT, bk, WvT, bv,
                                                  Qsb, Kb, Vt);
    attn_mfma<<<dim3(8, NH_, B_), 256, 0, stream>>>(Qsb, Kb, Vt, Ah);
    proj_mfma<<<dim3(64, B_), 256, 0, stream>>>(Ah, WoT, bo, out);
}